// Round 1
// baseline (292.746 us; speedup 1.0000x reference)
//
#include <hip/hip_runtime.h>

typedef unsigned short u16;
typedef unsigned int u32;
typedef __attribute__((ext_vector_type(8))) short s16x8;
typedef __attribute__((ext_vector_type(4))) float f32x4;

#define MB (1ull << 20)

__device__ __forceinline__ u16 f2bf(float f) {
  u32 u = __float_as_uint(f);
  u32 r = (u + 0x7fffu + ((u >> 16) & 1u)) >> 16;
  return (u16)r;
}

__device__ __forceinline__ void gload16(const u16* g, u16* l) {
  __builtin_amdgcn_global_load_lds((const __attribute__((address_space(1))) void*)g,
                                   (__attribute__((address_space(3))) void*)l, 16, 0, 0);
}

// ---------------- positional encoding: xf = x + pe (f32), xb = bf16(xf) ----------------
__global__ __launch_bounds__(256) void k_posenc(const float* __restrict__ x,
                                                float* __restrict__ xf, u16* __restrict__ xb) {
  int idx = blockIdx.x * 256 + threadIdx.x;
  int col = idx & 511;
  int srow = (idx >> 9) & 2047;
  int i2 = col >> 1;
  float div = expf((float)i2 * -0.03597789207803196f);  // exp(2*i2 * -ln(10000)/512)
  float ang = (float)srow * div;
  float pe = (col & 1) ? cosf(ang) : sinf(ang);
  float v = x[idx] + pe;
  xf[idx] = v;
  xb[idx] = f2bf(v);
}

// ---------------- transpose + cast: W[K][N] f32 -> Wt[N][K] bf16 ----------------
__global__ __launch_bounds__(256) void k_tcast(const float* __restrict__ W, u16* __restrict__ Wt,
                                               int K, int N) {
  __shared__ float tile[32][33];
  int k0 = blockIdx.x * 32, n0 = blockIdx.y * 32;
  int tx = threadIdx.x & 31, ty = threadIdx.x >> 5;  // ty 0..7
  #pragma unroll
  for (int i = 0; i < 32; i += 8)
    tile[ty + i][tx] = W[(size_t)(k0 + ty + i) * N + n0 + tx];
  __syncthreads();
  #pragma unroll
  for (int i = 0; i < 32; i += 8)
    Wt[(size_t)(n0 + ty + i) * K + k0 + tx] = f2bf(tile[tx][ty + i]);
}

__global__ void k_cat3(const float* __restrict__ a, const float* __restrict__ b,
                       const float* __restrict__ c, float* __restrict__ o) {
  int t = blockIdx.x * 256 + threadIdx.x;  // < 1536
  float v = (t < 512) ? a[t] : ((t < 1024) ? b[t - 512] : c[t - 1024]);
  o[t] = v;
}

// ---------------- bf16 MFMA GEMM: C[M,N] = A[M,K] @ Bt[N,K]^T + bias ----------------
// 128x128 tile, BK=64, 4 waves (2x2), global_load_lds staging, 3-bit XOR LDS swizzle.
#define GBM 128
#define GBK 64

template <bool RELU, bool WF32, bool WBF16>
__global__ __launch_bounds__(256) void k_gemm(const u16* __restrict__ A, const u16* __restrict__ Bt,
                                              const float* __restrict__ bias,
                                              float* __restrict__ Cf, u16* __restrict__ Cb,
                                              int N, int K) {
  __shared__ u16 lA[GBM * GBK];
  __shared__ u16 lB[GBM * GBK];
  int t = threadIdx.x;
  int lane = t & 63;
  int w = t >> 6;
  int wm = w >> 1, wn = w & 1;
  int g = lane >> 4, c = lane & 15;
  size_t tm = (size_t)blockIdx.x * GBM;
  size_t tn = (size_t)blockIdx.y * GBM;

  f32x4 acc[4][4];
  #pragma unroll
  for (int i = 0; i < 4; i++)
    #pragma unroll
    for (int j = 0; j < 4; j++) acc[i][j] = (f32x4){0.f, 0.f, 0.f, 0.f};

  for (int k0 = 0; k0 < K; k0 += GBK) {
    __syncthreads();
    #pragma unroll
    for (int i = 0; i < 4; i++) {
      int ch = t + i * 256;                    // 1024 chunks of 16B per tile
      int row = ch >> 3;
      int koff = ((ch ^ row) & 7) << 3;        // pre-swizzled source slot
      gload16(A + (tm + row) * K + k0 + koff, lA + ch * 8);
      gload16(Bt + (tn + row) * K + k0 + koff, lB + ch * 8);
    }
    __syncthreads();
    #pragma unroll
    for (int kh = 0; kh < 2; kh++) {
      int sl = ((g + 4 * kh) ^ (c & 7)) << 3;  // swizzled k-slot (row&7 == c&7)
      s16x8 af[4], bf[4];
      #pragma unroll
      for (int i = 0; i < 4; i++) {
        af[i] = *(const s16x8*)&lA[(wm * 64 + i * 16 + c) * GBK + sl];
        bf[i] = *(const s16x8*)&lB[(wn * 64 + i * 16 + c) * GBK + sl];
      }
      #pragma unroll
      for (int i = 0; i < 4; i++)
        #pragma unroll
        for (int j = 0; j < 4; j++)
          acc[i][j] = __builtin_amdgcn_mfma_f32_16x16x32_bf16(af[i], bf[j], acc[i][j], 0, 0, 0);
    }
  }
  #pragma unroll
  for (int j = 0; j < 4; j++) {
    size_t col = tn + wn * 64 + j * 16 + c;
    float bv = bias[col];
    #pragma unroll
    for (int i = 0; i < 4; i++) {
      size_t row0 = tm + wm * 64 + i * 16 + g * 4;
      #pragma unroll
      for (int r = 0; r < 4; r++) {
        float v = acc[i][j][r] + bv;
        if (RELU) v = fmaxf(v, 0.0f);
        if (WF32) Cf[(row0 + r) * N + col] = v;
        if (WBF16) Cb[(row0 + r) * N + col] = f2bf(v);
      }
    }
  }
}

// ---------------- transpose V out of fused qkv: vT[bh][d][s] ----------------
__global__ __launch_bounds__(256) void k_vt(const u16* __restrict__ qkv, u16* __restrict__ vT) {
  __shared__ u16 tile[32][33];
  int bh = blockIdx.z;
  int b = bh >> 3, h = bh & 7;
  int s0 = blockIdx.x * 32, d0 = blockIdx.y * 32;
  int tx = threadIdx.x & 31, ty = threadIdx.x >> 5;
  #pragma unroll
  for (int i = 0; i < 32; i += 8)
    tile[ty + i][tx] = qkv[(size_t)(b * 2048 + s0 + ty + i) * 1536 + 1024 + h * 64 + d0 + tx];
  __syncthreads();
  #pragma unroll
  for (int i = 0; i < 32; i += 8)
    vT[(size_t)(bh * 64 + d0 + ty + i) * 2048 + s0 + tx] = tile[tx][ty + i];
}

// ---------------- flash attention, MFMA 16x16x32, online softmax ----------------
// block = 4 waves; wave owns 16 q-rows; K/V tiles of 64 keys staged in swizzled LDS.
__global__ __launch_bounds__(256) void k_attn(const u16* __restrict__ qkv, const u16* __restrict__ vT,
                                              u16* __restrict__ ctx) {
  __shared__ u16 lK[64 * 64];
  __shared__ u16 lV[64 * 64];     // holds V^T tile: [dim][key]
  __shared__ u16 lP[4][16 * 64];  // per-wave P tile [qrow][key]
  int t = threadIdx.x;
  int w = t >> 6, lane = t & 63;
  int g = lane >> 4, c = lane & 15;
  int bh = blockIdx.y;
  int b = bh >> 3, h = bh & 7;
  int q0 = blockIdx.x * 64 + w * 16;

  // resident Q fragments (A-operand): row = c, k = g*8 (+32)
  const u16* qbase = qkv + (size_t)(b * 2048 + q0 + c) * 1536 + h * 64 + g * 8;
  s16x8 qf0 = *(const s16x8*)qbase;
  s16x8 qf1 = *(const s16x8*)(qbase + 32);

  float m[4], l[4];
  f32x4 o[4];
  #pragma unroll
  for (int r = 0; r < 4; r++) { m[r] = -1e30f; l[r] = 0.f; }
  #pragma unroll
  for (int nf = 0; nf < 4; nf++) o[nf] = (f32x4){0.f, 0.f, 0.f, 0.f};

  const float k1 = 0.125f * 1.4426950408889634f;  // 1/sqrt(dk) * log2(e)
  u16* lPw = lP[w];

  for (int t0 = 0; t0 < 2048; t0 += 64) {
    __syncthreads();
    #pragma unroll
    for (int i = 0; i < 2; i++) {
      int ch = t + i * 256;        // 512 chunks of 16B per tile
      int key = ch >> 3;           // row index (key for lK, dim for lV)
      int off = ((ch ^ key) & 7) << 3;
      gload16(qkv + (size_t)(b * 2048 + t0 + key) * 1536 + 512 + h * 64 + off, lK + ch * 8);
      gload16(vT + (size_t)(bh * 64 + key) * 2048 + t0 + off, lV + ch * 8);
    }
    __syncthreads();

    // S = Q @ K^T (scaled to log2 domain)
    float z[4][4];
    int sl0 = (g ^ (c & 7)) << 3;
    int sl1 = ((g + 4) ^ (c & 7)) << 3;
    #pragma unroll
    for (int nf = 0; nf < 4; nf++) {
      s16x8 kf0 = *(const s16x8*)&lK[(nf * 16 + c) * 64 + sl0];
      s16x8 kf1 = *(const s16x8*)&lK[(nf * 16 + c) * 64 + sl1];
      f32x4 s = (f32x4){0.f, 0.f, 0.f, 0.f};
      s = __builtin_amdgcn_mfma_f32_16x16x32_bf16(qf0, kf0, s, 0, 0, 0);
      s = __builtin_amdgcn_mfma_f32_16x16x32_bf16(qf1, kf1, s, 0, 0, 0);
      #pragma unroll
      for (int r = 0; r < 4; r++) z[nf][r] = s[r] * k1;
    }
    // per-row running max (rows live in 16-lane groups, reg r -> row g*4+r)
    float tm4[4], al[4], ps[4];
    #pragma unroll
    for (int r = 0; r < 4; r++) {
      float v = fmaxf(fmaxf(z[0][r], z[1][r]), fmaxf(z[2][r], z[3][r]));
      #pragma unroll
      for (int d = 1; d < 16; d <<= 1) v = fmaxf(v, __shfl_xor(v, d, 64));
      tm4[r] = v;
    }
    #pragma unroll
    for (int r = 0; r < 4; r++) {
      float mn = fmaxf(m[r], tm4[r]);
      al[r] = exp2f(m[r] - mn);
      m[r] = mn;
      ps[r] = 0.f;
    }
    // P = exp2(z - m), write bf16 to swizzled LDS, accumulate row sums
    #pragma unroll
    for (int nf = 0; nf < 4; nf++)
      #pragma unroll
      for (int r = 0; r < 4; r++) {
        float p = exp2f(z[nf][r] - m[r]);
        ps[r] += p;
        int prow = g * 4 + r;
        lPw[prow * 64 + ((nf * 16 + c) ^ ((prow & 7) << 3))] = f2bf(p);
      }
    #pragma unroll
    for (int r = 0; r < 4; r++) {
      float v = ps[r];
      #pragma unroll
      for (int d = 1; d < 16; d <<= 1) v += __shfl_xor(v, d, 64);
      l[r] = l[r] * al[r] + v;
    }
    #pragma unroll
    for (int nf = 0; nf < 4; nf++)
      #pragma unroll
      for (int r = 0; r < 4; r++) o[nf][r] *= al[r];

    asm volatile("s_waitcnt lgkmcnt(0)" ::: "memory");  // P writes visible to whole wave

    // O += P @ V
    #pragma unroll
    for (int kh = 0; kh < 2; kh++) {
      s16x8 pf = *(const s16x8*)&lPw[c * 64 + ((kh * 32 + g * 8) ^ ((c & 7) << 3))];
      #pragma unroll
      for (int nf = 0; nf < 4; nf++) {
        s16x8 vf = *(const s16x8*)&lV[(nf * 16 + c) * 64 + (((g + 4 * kh) ^ (c & 7)) << 3)];
        o[nf] = __builtin_amdgcn_mfma_f32_16x16x32_bf16(pf, vf, o[nf], 0, 0, 0);
      }
    }
  }
  float inv[4];
  #pragma unroll
  for (int r = 0; r < 4; r++) inv[r] = 1.0f / l[r];
  #pragma unroll
  for (int nf = 0; nf < 4; nf++)
    #pragma unroll
    for (int r = 0; r < 4; r++) {
      float v = o[nf][r] * inv[r];
      ctx[(size_t)(b * 2048 + q0 + g * 4 + r) * 512 + h * 64 + nf * 16 + c] = f2bf(v);
    }
}

// ---------------- residual add + LayerNorm (D=512), optional bf16 copy ----------------
template <bool WB>
__global__ __launch_bounds__(256) void k_addln(const float* __restrict__ A, const float* __restrict__ Bv,
                                               const float* __restrict__ G, const float* __restrict__ Bb,
                                               float* __restrict__ Of, u16* __restrict__ Ob) {
  int row = blockIdx.x;
  int t = threadIdx.x;
  size_t base = (size_t)row * 512;
  float x0 = A[base + t] + Bv[base + t];
  float x1 = A[base + t + 256] + Bv[base + t + 256];
  float s = x0 + x1;
  #pragma unroll
  for (int d = 1; d < 64; d <<= 1) s += __shfl_xor(s, d, 64);
  __shared__ float red[8];
  int w = t >> 6, lane = t & 63;
  if (lane == 0) red[w] = s;
  __syncthreads();
  float mu = (red[0] + red[1] + red[2] + red[3]) * (1.0f / 512.0f);
  float d0 = x0 - mu, d1 = x1 - mu;
  float vs = d0 * d0 + d1 * d1;
  #pragma unroll
  for (int d = 1; d < 64; d <<= 1) vs += __shfl_xor(vs, d, 64);
  if (lane == 0) red[4 + w] = vs;
  __syncthreads();
  float var = (red[4] + red[5] + red[6] + red[7]) * (1.0f / 512.0f);
  float rs = rsqrtf(var + 1e-5f);
  float o0 = d0 * rs * G[t] + Bb[t];
  float o1 = d1 * rs * G[t + 256] + Bb[t + 256];
  Of[base + t] = o0;
  Of[base + t + 256] = o1;
  if (WB) {
    Ob[base + t] = f2bf(o0);
    Ob[base + t + 256] = f2bf(o1);
  }
}

// ---------------- launch ----------------
extern "C" void kernel_launch(void* const* d_in, const int* in_sizes, int n_in,
                              void* d_out, int out_size, void* d_ws, size_t ws_size,
                              hipStream_t stream) {
  const float* x = (const float*)d_in[0];
  const float* Wq = (const float*)d_in[1];
  const float* bq = (const float*)d_in[2];
  const float* Wk = (const float*)d_in[3];
  const float* bk = (const float*)d_in[4];
  const float* Wv = (const float*)d_in[5];
  const float* bv = (const float*)d_in[6];
  const float* Wo = (const float*)d_in[7];
  const float* bo = (const float*)d_in[8];
  const float* g1 = (const float*)d_in[9];
  const float* b1 = (const float*)d_in[10];
  const float* Wff1 = (const float*)d_in[11];
  const float* bff1 = (const float*)d_in[12];
  const float* Wff2 = (const float*)d_in[13];
  const float* bff2 = (const float*)d_in[14];
  const float* g2 = (const float*)d_in[15];
  const float* b2 = (const float*)d_in[16];

  char* ws = (char*)d_ws;
  float* xpe_f = (float*)(ws + 0);            // 16MB
  u16* xpe_b = (u16*)(ws + 16 * MB);          // 8MB
  u16* qkv = (u16*)(ws + 24 * MB);            // 24MB  [8192][1536]
  u16* vT = (u16*)(ws + 48 * MB);             // 8MB   [32][64][2048]
  u16* ctx = (u16*)(ws + 56 * MB);            // 8MB   [8192][512]
  float* ao = (float*)(ws + 64 * MB);         // 16MB  attn_out / ff2 out
  float* hf = (float*)(ws + 80 * MB);         // 16MB
  u16* hb = (u16*)(ws + 96 * MB);             // 8MB
  u16* ff1 = (u16*)(ws + 24 * MB);            // 32MB, aliases qkv+vT (dead by then)
  u16* WqkvT = (u16*)(ws + 104 * MB);         // 1.5MB [1536][512]
  u16* WoT = (u16*)(ws + 106 * MB);           // 0.5MB
  u16* Wff1T = (u16*)(ws + 107 * MB);         // 2MB [2048][512]
  u16* Wff2T = (u16*)(ws + 109 * MB);         // 2MB [512][2048]
  float* bqkv = (float*)(ws + 111 * MB);      // 6KB
  (void)in_sizes; (void)n_in; (void)out_size; (void)ws_size;

  k_posenc<<<16384, 256, 0, stream>>>(x, xpe_f, xpe_b);
  k_tcast<<<dim3(16, 16), 256, 0, stream>>>(Wq, WqkvT, 512, 512);
  k_tcast<<<dim3(16, 16), 256, 0, stream>>>(Wk, WqkvT + 512 * 512, 512, 512);
  k_tcast<<<dim3(16, 16), 256, 0, stream>>>(Wv, WqkvT + 2 * 512 * 512, 512, 512);
  k_tcast<<<dim3(16, 16), 256, 0, stream>>>(Wo, WoT, 512, 512);
  k_tcast<<<dim3(16, 64), 256, 0, stream>>>(Wff1, Wff1T, 512, 2048);
  k_tcast<<<dim3(64, 16), 256, 0, stream>>>(Wff2, Wff2T, 2048, 512);
  k_cat3<<<6, 256, 0, stream>>>(bq, bk, bv, bqkv);

  // fused QKV projection: [8192,512] @ [512,1536]
  k_gemm<false, false, true><<<dim3(64, 12), 256, 0, stream>>>(xpe_b, WqkvT, bqkv, nullptr, qkv, 1536, 512);
  k_vt<<<dim3(64, 2, 32), 256, 0, stream>>>(qkv, vT);
  k_attn<<<dim3(32, 32), 256, 0, stream>>>(qkv, vT, ctx);
  // O projection
  k_gemm<false, true, false><<<dim3(64, 4), 256, 0, stream>>>(ctx, WoT, bo, ao, nullptr, 512, 512);
  k_addln<true><<<8192, 256, 0, stream>>>(xpe_f, ao, g1, b1, hf, hb);
  // FFN
  k_gemm<true, false, true><<<dim3(64, 16), 256, 0, stream>>>(hb, Wff1T, bff1, nullptr, ff1, 2048, 512);
  k_gemm<false, true, false><<<dim3(64, 4), 256, 0, stream>>>(ff1, Wff2T, bff2, ao, nullptr, 512, 2048);
  k_addln<false><<<8192, 256, 0, stream>>>(hf, ao, g2, b2, (float*)d_out, nullptr);
}

// Round 2
// 222.765 us; speedup vs baseline: 1.3141x; 1.3141x over previous
//
#include <hip/hip_runtime.h>

typedef unsigned short u16;
typedef unsigned int u32;
typedef __attribute__((ext_vector_type(8))) short s16x8;
typedef __attribute__((ext_vector_type(4))) float f32x4;
typedef __attribute__((ext_vector_type(16))) float f32x16;
typedef __attribute__((ext_vector_type(2))) u32 u32x2;
typedef __attribute__((ext_vector_type(4))) u32 u32x4;

#define MB (1ull << 20)

__device__ __forceinline__ u16 f2bf(float f) {
  u32 u = __float_as_uint(f);
  u32 r = (u + 0x7fffu + ((u >> 16) & 1u)) >> 16;
  return (u16)r;
}

__device__ __forceinline__ u32 cvtpk(float lo, float hi) {
  u32 r;
  asm("v_cvt_pk_bf16_f32 %0, %1, %2" : "=v"(r) : "v"(lo), "v"(hi));
  return r;
}

__device__ __forceinline__ void gload16(const u16* g, u16* l) {
  __builtin_amdgcn_global_load_lds((const __attribute__((address_space(1))) void*)g,
                                   (__attribute__((address_space(3))) void*)l, 16, 0, 0);
}

// ---------------- positional encoding: xf = x + pe (f32), xb = bf16(xf) ----------------
__global__ __launch_bounds__(256) void k_posenc(const float* __restrict__ x,
                                                float* __restrict__ xf, u16* __restrict__ xb) {
  int idx = blockIdx.x * 256 + threadIdx.x;
  int col = idx & 511;
  int srow = (idx >> 9) & 2047;
  int i2 = col >> 1;
  float div = expf((float)i2 * -0.03597789207803196f);  // exp(2*i2 * -ln(10000)/512)
  float ang = (float)srow * div;
  float pe = (col & 1) ? cosf(ang) : sinf(ang);
  float v = x[idx] + pe;
  xf[idx] = v;
  xb[idx] = f2bf(v);
}

// ---------------- transpose + cast: W[K][N] f32 -> Wt[N][K] bf16 ----------------
__global__ __launch_bounds__(256) void k_tcast(const float* __restrict__ W, u16* __restrict__ Wt,
                                               int K, int N) {
  __shared__ float tile[32][33];
  int k0 = blockIdx.x * 32, n0 = blockIdx.y * 32;
  int tx = threadIdx.x & 31, ty = threadIdx.x >> 5;  // ty 0..7
  #pragma unroll
  for (int i = 0; i < 32; i += 8)
    tile[ty + i][tx] = W[(size_t)(k0 + ty + i) * N + n0 + tx];
  __syncthreads();
  #pragma unroll
  for (int i = 0; i < 32; i += 8)
    Wt[(size_t)(n0 + ty + i) * K + k0 + tx] = f2bf(tile[tx][ty + i]);
}

__global__ void k_cat3(const float* __restrict__ a, const float* __restrict__ b,
                       const float* __restrict__ c, float* __restrict__ o) {
  int t = blockIdx.x * 256 + threadIdx.x;  // < 1536
  float v = (t < 512) ? a[t] : ((t < 1024) ? b[t - 512] : c[t - 1024]);
  o[t] = v;
}

// ---------------- bf16 MFMA GEMM: C[M,N] = A[M,K] @ Bt[N,K]^T + bias ----------------
// 128x128 tile, BK=64, 4 waves (2x2), global_load_lds staging, 3-bit XOR LDS swizzle.
#define GBM 128
#define GBK 64

template <bool RELU, bool WF32, bool WBF16>
__global__ __launch_bounds__(256) void k_gemm(const u16* __restrict__ A, const u16* __restrict__ Bt,
                                              const float* __restrict__ bias,
                                              float* __restrict__ Cf, u16* __restrict__ Cb,
                                              int N, int K) {
  __shared__ u16 lA[GBM * GBK];
  __shared__ u16 lB[GBM * GBK];
  int t = threadIdx.x;
  int lane = t & 63;
  int w = t >> 6;
  int wm = w >> 1, wn = w & 1;
  int g = lane >> 4, c = lane & 15;
  size_t tm = (size_t)blockIdx.x * GBM;
  size_t tn = (size_t)blockIdx.y * GBM;

  f32x4 acc[4][4];
  #pragma unroll
  for (int i = 0; i < 4; i++)
    #pragma unroll
    for (int j = 0; j < 4; j++) acc[i][j] = (f32x4){0.f, 0.f, 0.f, 0.f};

  for (int k0 = 0; k0 < K; k0 += GBK) {
    __syncthreads();
    #pragma unroll
    for (int i = 0; i < 4; i++) {
      int ch = t + i * 256;                    // 1024 chunks of 16B per tile
      int row = ch >> 3;
      int koff = ((ch ^ row) & 7) << 3;        // pre-swizzled source slot
      gload16(A + (tm + row) * K + k0 + koff, lA + ch * 8);
      gload16(Bt + (tn + row) * K + k0 + koff, lB + ch * 8);
    }
    __syncthreads();
    #pragma unroll
    for (int kh = 0; kh < 2; kh++) {
      int sl = ((g + 4 * kh) ^ (c & 7)) << 3;  // swizzled k-slot (row&7 == c&7)
      s16x8 af[4], bf[4];
      #pragma unroll
      for (int i = 0; i < 4; i++) {
        af[i] = *(const s16x8*)&lA[(wm * 64 + i * 16 + c) * GBK + sl];
        bf[i] = *(const s16x8*)&lB[(wn * 64 + i * 16 + c) * GBK + sl];
      }
      #pragma unroll
      for (int i = 0; i < 4; i++)
        #pragma unroll
        for (int j = 0; j < 4; j++)
          acc[i][j] = __builtin_amdgcn_mfma_f32_16x16x32_bf16(af[i], bf[j], acc[i][j], 0, 0, 0);
    }
  }
  #pragma unroll
  for (int j = 0; j < 4; j++) {
    size_t col = tn + wn * 64 + j * 16 + c;
    float bv = bias[col];
    #pragma unroll
    for (int i = 0; i < 4; i++) {
      size_t row0 = tm + wm * 64 + i * 16 + g * 4;
      #pragma unroll
      for (int r = 0; r < 4; r++) {
        float v = acc[i][j][r] + bv;
        if (RELU) v = fmaxf(v, 0.0f);
        if (WF32) Cf[(row0 + r) * N + col] = v;
        if (WBF16) Cb[(row0 + r) * N + col] = f2bf(v);
      }
    }
  }
}

// ---------------- transpose V out of fused qkv: vT[bh][d][s] ----------------
__global__ __launch_bounds__(256) void k_vt(const u16* __restrict__ qkv, u16* __restrict__ vT) {
  __shared__ u16 tile[32][33];
  int bh = blockIdx.z;
  int b = bh >> 3, h = bh & 7;
  int s0 = blockIdx.x * 32, d0 = blockIdx.y * 32;
  int tx = threadIdx.x & 31, ty = threadIdx.x >> 5;
  #pragma unroll
  for (int i = 0; i < 32; i += 8)
    tile[ty + i][tx] = qkv[(size_t)(b * 2048 + s0 + ty + i) * 1536 + 1024 + h * 64 + d0 + tx];
  __syncthreads();
  #pragma unroll
  for (int i = 0; i < 32; i += 8)
    vT[(size_t)(bh * 64 + d0 + ty + i) * 2048 + s0 + tx] = tile[tx][ty + i];
}

// ---------------- flash attention, swapped-operand 32x32x16 MFMA, in-register softmax ----
// Block = 4 waves, each wave owns 32 q-rows. S^T = K @ Q^T so lane q = lane&31 holds its
// whole softmax row in registers; P packs via cvt_pk + permlane32_swap straight into the
// B-operand of O^T = V^T @ P^T. K/V tiles (64 keys) staged via swizzled global_load_lds.
__global__ __launch_bounds__(256) void k_attn(const u16* __restrict__ qkv, const u16* __restrict__ vT,
                                              u16* __restrict__ ctx) {
  __shared__ u16 lK[64 * 64];   // [key][d], XOR-swizzled 16B slots
  __shared__ u16 lV[64 * 64];   // [d][key], XOR-swizzled 16B slots
  int t = threadIdx.x;
  int w = t >> 6, lane = t & 63;
  int ql = lane & 31, hi = lane >> 5;
  int bh = blockIdx.y;
  int b = bh >> 3, h = bh & 7;
  int q0 = blockIdx.x * 128 + w * 32;
  int r7 = ql & 7;

  // Q fragments (B-operand): col=q=ql, k-dim = ks*16 + hi*8 + [0..7]
  const u16* qbase = qkv + (size_t)(b * 2048 + q0 + ql) * 1536 + h * 64 + hi * 8;
  s16x8 qf[4];
  #pragma unroll
  for (int ks = 0; ks < 4; ks++) qf[ks] = *(const s16x8*)(qbase + ks * 16);

  float m = -1e30f, l = 0.f;
  f32x16 o0, o1;  // O^T accumulators: d-blocks 0..31 / 32..63, col = q (lane-local)
  #pragma unroll
  for (int i = 0; i < 16; i++) { o0[i] = 0.f; o1[i] = 0.f; }

  const float k1 = 0.125f * 1.4426950408889634f;  // 1/sqrt(dk) * log2(e)

  for (int t0 = 0; t0 < 2048; t0 += 64) {
    __syncthreads();
    #pragma unroll
    for (int i = 0; i < 2; i++) {
      int ch = t + i * 256;        // 512 chunks of 16B per tile
      int row = ch >> 3;
      int off = ((ch ^ row) & 7) << 3;
      gload16(qkv + (size_t)(b * 2048 + t0 + row) * 1536 + 512 + h * 64 + off, lK + ch * 8);
      gload16(vT + (size_t)(bh * 64 + row) * 2048 + t0 + off, lV + ch * 8);
    }
    __syncthreads();

    // S^T[key][q] = K @ Q^T ; lane holds q=ql, keys (reg&3)+8*(reg>>2)+4*hi (+32 for s1)
    f32x16 s0, s1;
    #pragma unroll
    for (int i = 0; i < 16; i++) { s0[i] = 0.f; s1[i] = 0.f; }
    #pragma unroll
    for (int ks = 0; ks < 4; ks++) {
      int so = ((ks * 2 + hi) ^ r7) << 3;
      s16x8 kf0 = *(const s16x8*)&lK[ql * 64 + so];
      s16x8 kf1 = *(const s16x8*)&lK[(32 + ql) * 64 + so];
      s0 = __builtin_amdgcn_mfma_f32_32x32x16_bf16(kf0, qf[ks], s0, 0, 0, 0);
      s1 = __builtin_amdgcn_mfma_f32_32x32x16_bf16(kf1, qf[ks], s1, 0, 0, 0);
    }

    // online softmax, all lane-local for q=ql (keys split across hi halves)
    f32x16 tmx;
    #pragma unroll
    for (int i = 0; i < 16; i++) tmx[i] = fmaxf(s0[i], s1[i]);
    #pragma unroll
    for (int i = 0; i < 8; i++) tmx[i] = fmaxf(tmx[i], tmx[i + 8]);
    #pragma unroll
    for (int i = 0; i < 4; i++) tmx[i] = fmaxf(tmx[i], tmx[i + 4]);
    float rm = fmaxf(fmaxf(tmx[0], tmx[1]), fmaxf(tmx[2], tmx[3]));
    rm = fmaxf(rm, __shfl_xor(rm, 32, 64));
    float mn = fmaxf(m, rm * k1);
    float al = __builtin_amdgcn_exp2f(m - mn);
    m = mn;
    float ps[4] = {0.f, 0.f, 0.f, 0.f};
    #pragma unroll
    for (int i = 0; i < 16; i++) {
      float p = __builtin_amdgcn_exp2f(fmaf(s0[i], k1, -m));
      s0[i] = p;
      ps[i & 3] += p;
    }
    #pragma unroll
    for (int i = 0; i < 16; i++) {
      float p = __builtin_amdgcn_exp2f(fmaf(s1[i], k1, -m));
      s1[i] = p;
      ps[i & 3] += p;
    }
    float pssum = (ps[0] + ps[1]) + (ps[2] + ps[3]);
    pssum += __shfl_xor(pssum, 32, 64);
    l = l * al + pssum;
    #pragma unroll
    for (int i = 0; i < 16; i++) { o0[i] *= al; o1[i] *= al; }

    // P pack (cvt_pk + permlane32_swap) -> B-operand frags; O^T += V^T @ P^T
    auto pv = [&](const f32x16& sv, int kb) {
      u32 a0 = cvtpk(sv[0], sv[1]), a1 = cvtpk(sv[2], sv[3]);
      u32 a2 = cvtpk(sv[4], sv[5]), a3 = cvtpk(sv[6], sv[7]);
      u32 b0 = cvtpk(sv[8], sv[9]), b1 = cvtpk(sv[10], sv[11]);
      u32 b2 = cvtpk(sv[12], sv[13]), b3 = cvtpk(sv[14], sv[15]);
      asm("v_permlane32_swap_b32 %0, %1" : "+v"(a0), "+v"(a2));
      asm("v_permlane32_swap_b32 %0, %1" : "+v"(a1), "+v"(a3));
      asm("v_permlane32_swap_b32 %0, %1" : "+v"(b0), "+v"(b2));
      asm("v_permlane32_swap_b32 %0, %1" : "+v"(b1), "+v"(b3));
      u32x4 w0v = {a0, a1, a2, a3};   // keys kb*32 + hi*8 + [0..7]
      u32x4 w1v = {b0, b1, b2, b3};   // keys kb*32 + 16 + hi*8 + [0..7]
      s16x8 pf0 = __builtin_bit_cast(s16x8, w0v);
      s16x8 pf1 = __builtin_bit_cast(s16x8, w1v);
      int base0 = ((kb * 4 + hi) ^ r7) << 3;
      int base1 = ((kb * 4 + 2 + hi) ^ r7) << 3;
      s16x8 vf00 = *(const s16x8*)&lV[ql * 64 + base0];
      s16x8 vf01 = *(const s16x8*)&lV[ql * 64 + base1];
      s16x8 vf10 = *(const s16x8*)&lV[(32 + ql) * 64 + base0];
      s16x8 vf11 = *(const s16x8*)&lV[(32 + ql) * 64 + base1];
      o0 = __builtin_amdgcn_mfma_f32_32x32x16_bf16(vf00, pf0, o0, 0, 0, 0);
      o0 = __builtin_amdgcn_mfma_f32_32x32x16_bf16(vf01, pf1, o0, 0, 0, 0);
      o1 = __builtin_amdgcn_mfma_f32_32x32x16_bf16(vf10, pf0, o1, 0, 0, 0);
      o1 = __builtin_amdgcn_mfma_f32_32x32x16_bf16(vf11, pf1, o1, 0, 0, 0);
    };
    pv(s0, 0);
    pv(s1, 1);
  }

  // normalize + write ctx[b, q, h*64 + d]; lane's q fixed, regs 4k+j -> d = 8k + 4hi + j
  float inv = 1.0f / l;
  size_t obase = (size_t)(b * 2048 + q0 + ql) * 512 + h * 64;
  #pragma unroll
  for (int k = 0; k < 4; k++) {
    u32 lo0 = cvtpk(o0[4 * k] * inv, o0[4 * k + 1] * inv);
    u32 hi0 = cvtpk(o0[4 * k + 2] * inv, o0[4 * k + 3] * inv);
    u32x2 p0 = {lo0, hi0};
    *(u32x2*)&ctx[obase + 8 * k + 4 * hi] = p0;
    u32 lo1 = cvtpk(o1[4 * k] * inv, o1[4 * k + 1] * inv);
    u32 hi1 = cvtpk(o1[4 * k + 2] * inv, o1[4 * k + 3] * inv);
    u32x2 p1 = {lo1, hi1};
    *(u32x2*)&ctx[obase + 32 + 8 * k + 4 * hi] = p1;
  }
}

// ---------------- residual add + LayerNorm (D=512), optional bf16 copy ----------------
template <bool WB>
__global__ __launch_bounds__(256) void k_addln(const float* __restrict__ A, const float* __restrict__ Bv,
                                               const float* __restrict__ G, const float* __restrict__ Bb,
                                               float* __restrict__ Of, u16* __restrict__ Ob) {
  int row = blockIdx.x;
  int t = threadIdx.x;
  size_t base = (size_t)row * 512;
  float x0 = A[base + t] + Bv[base + t];
  float x1 = A[base + t + 256] + Bv[base + t + 256];
  float s = x0 + x1;
  #pragma unroll
  for (int d = 1; d < 64; d <<= 1) s += __shfl_xor(s, d, 64);
  __shared__ float red[8];
  int w = t >> 6, lane = t & 63;
  if (lane == 0) red[w] = s;
  __syncthreads();
  float mu = (red[0] + red[1] + red[2] + red[3]) * (1.0f / 512.0f);
  float d0 = x0 - mu, d1 = x1 - mu;
  float vs = d0 * d0 + d1 * d1;
  #pragma unroll
  for (int d = 1; d < 64; d <<= 1) vs += __shfl_xor(vs, d, 64);
  if (lane == 0) red[4 + w] = vs;
  __syncthreads();
  float var = (red[4] + red[5] + red[6] + red[7]) * (1.0f / 512.0f);
  float rs = rsqrtf(var + 1e-5f);
  float o0 = d0 * rs * G[t] + Bb[t];
  float o1 = d1 * rs * G[t + 256] + Bb[t + 256];
  Of[base + t] = o0;
  Of[base + t + 256] = o1;
  if (WB) {
    Ob[base + t] = f2bf(o0);
    Ob[base + t + 256] = f2bf(o1);
  }
}

// ---------------- launch ----------------
extern "C" void kernel_launch(void* const* d_in, const int* in_sizes, int n_in,
                              void* d_out, int out_size, void* d_ws, size_t ws_size,
                              hipStream_t stream) {
  const float* x = (const float*)d_in[0];
  const float* Wq = (const float*)d_in[1];
  const float* bq = (const float*)d_in[2];
  const float* Wk = (const float*)d_in[3];
  const float* bk = (const float*)d_in[4];
  const float* Wv = (const float*)d_in[5];
  const float* bv = (const float*)d_in[6];
  const float* Wo = (const float*)d_in[7];
  const float* bo = (const float*)d_in[8];
  const float* g1 = (const float*)d_in[9];
  const float* b1 = (const float*)d_in[10];
  const float* Wff1 = (const float*)d_in[11];
  const float* bff1 = (const float*)d_in[12];
  const float* Wff2 = (const float*)d_in[13];
  const float* bff2 = (const float*)d_in[14];
  const float* g2 = (const float*)d_in[15];
  const float* b2 = (const float*)d_in[16];

  char* ws = (char*)d_ws;
  float* xpe_f = (float*)(ws + 0);            // 16MB
  u16* xpe_b = (u16*)(ws + 16 * MB);          // 8MB
  u16* qkv = (u16*)(ws + 24 * MB);            // 24MB  [8192][1536]
  u16* vT = (u16*)(ws + 48 * MB);             // 8MB   [32][64][2048]
  u16* ctx = (u16*)(ws + 56 * MB);            // 8MB   [8192][512]
  float* ao = (float*)(ws + 64 * MB);         // 16MB  attn_out / ff2 out
  float* hf = (float*)(ws + 80 * MB);         // 16MB
  u16* hb = (u16*)(ws + 96 * MB);             // 8MB
  u16* ff1 = (u16*)(ws + 24 * MB);            // 32MB, aliases qkv+vT (dead by then)
  u16* WqkvT = (u16*)(ws + 104 * MB);         // 1.5MB [1536][512]
  u16* WoT = (u16*)(ws + 106 * MB);           // 0.5MB
  u16* Wff1T = (u16*)(ws + 107 * MB);         // 2MB [2048][512]
  u16* Wff2T = (u16*)(ws + 109 * MB);         // 2MB [512][2048]
  float* bqkv = (float*)(ws + 111 * MB);      // 6KB
  (void)in_sizes; (void)n_in; (void)out_size; (void)ws_size;

  k_posenc<<<16384, 256, 0, stream>>>(x, xpe_f, xpe_b);
  k_tcast<<<dim3(16, 16), 256, 0, stream>>>(Wq, WqkvT, 512, 512);
  k_tcast<<<dim3(16, 16), 256, 0, stream>>>(Wk, WqkvT + 512 * 512, 512, 512);
  k_tcast<<<dim3(16, 16), 256, 0, stream>>>(Wv, WqkvT + 2 * 512 * 512, 512, 512);
  k_tcast<<<dim3(16, 16), 256, 0, stream>>>(Wo, WoT, 512, 512);
  k_tcast<<<dim3(16, 64), 256, 0, stream>>>(Wff1, Wff1T, 512, 2048);
  k_tcast<<<dim3(64, 16), 256, 0, stream>>>(Wff2, Wff2T, 2048, 512);
  k_cat3<<<6, 256, 0, stream>>>(bq, bk, bv, bqkv);

  // fused QKV projection: [8192,512] @ [512,1536]
  k_gemm<false, false, true><<<dim3(64, 12), 256, 0, stream>>>(xpe_b, WqkvT, bqkv, nullptr, qkv, 1536, 512);
  k_vt<<<dim3(64, 2, 32), 256, 0, stream>>>(qkv, vT);
  k_attn<<<dim3(16, 32), 256, 0, stream>>>(qkv, vT, ctx);
  // O projection
  k_gemm<false, true, false><<<dim3(64, 4), 256, 0, stream>>>(ctx, WoT, bo, ao, nullptr, 512, 512);
  k_addln<true><<<8192, 256, 0, stream>>>(xpe_f, ao, g1, b1, hf, hb);
  // FFN
  k_gemm<true, false, true><<<dim3(64, 16), 256, 0, stream>>>(hb, Wff1T, bff1, nullptr, ff1, 2048, 512);
  k_gemm<false, true, false><<<dim3(64, 4), 256, 0, stream>>>(ff1, Wff2T, bff2, ao, nullptr, 512, 2048);
  k_addln<false><<<8192, 256, 0, stream>>>(hf, ao, g2, b2, (float*)d_out, nullptr);
}